// Round 1
// 197.678 us; speedup vs baseline: 1.4131x; 1.4131x over previous
//
#include <hip/hip_runtime.h>
#include <hip/hip_bf16.h>

// ---------------------------------------------------------------------------
// PagedHSTUInferLayer on MI355X (gfx950)
// LN -> GEMM1(bf16 MFMA, silu+bias, alpha folded into q cols) ->
// HSTU attention (t-split partial sums, 8-wave blocks, swapped QK^T) ->
// gated LN (sums the two t-partials) -> GEMM2(+residual, fp32 out)
// ---------------------------------------------------------------------------

typedef __attribute__((ext_vector_type(8))) short v8s;   // 8 x bf16 (4 VGPR)
typedef __attribute__((ext_vector_type(4))) float v4f;   // MFMA accumulator
typedef __attribute__((ext_vector_type(4))) unsigned short v4us;

#define D_HID 512
#define U_DIM 2048
#define NHEAD 4
#define DHEAD 128
#define BATCH 32
#define SEQ   256
#define HIST  2048
#define NTOK  8192
#define TTOT  2304                    // HIST + SEQ
#define ALPHA_ 0.08838834764831845f   // 1/sqrt(128)
#define EPS_   1e-5f

__device__ __forceinline__ unsigned short f2bf(float f) {
  unsigned int u = __float_as_uint(f);
  u += 0x7FFFu + ((u >> 16) & 1u);            // round-to-nearest-even
  return (unsigned short)(u >> 16);
}
__device__ __forceinline__ float bf2f(unsigned short s) {
  return __uint_as_float(((unsigned int)s) << 16);
}
__device__ __forceinline__ float siluf(float x) {
  return x / (1.0f + __expf(-x));
}

// ---------------------------------------------------------------------------
// LN over D=512 per row -> bf16. 4 waves/block, one row per wave.
// ---------------------------------------------------------------------------
__global__ __launch_bounds__(256) void ln_in_kernel(
    const float* __restrict__ x, const float* __restrict__ w,
    const float* __restrict__ b, unsigned short* __restrict__ out)
{
  int wid = threadIdx.x >> 6, lane = threadIdx.x & 63;
  int row = blockIdx.x * 4 + wid;
  const float* xr = x + (size_t)row * D_HID + lane * 8;
  float4 a0 = *(const float4*)xr;
  float4 a1 = *(const float4*)(xr + 4);
  float v[8] = {a0.x, a0.y, a0.z, a0.w, a1.x, a1.y, a1.z, a1.w};
  float s = 0.f, s2 = 0.f;
#pragma unroll
  for (int j = 0; j < 8; ++j) { s += v[j]; s2 += v[j] * v[j]; }
#pragma unroll
  for (int m = 1; m < 64; m <<= 1) { s += __shfl_xor(s, m, 64); s2 += __shfl_xor(s2, m, 64); }
  float mean = s * (1.f / D_HID);
  float var  = s2 * (1.f / D_HID) - mean * mean;
  float rstd = rsqrtf(var + EPS_);
  const float* wp = w + lane * 8; const float* bp = b + lane * 8;
  float4 w0 = *(const float4*)wp, w1 = *(const float4*)(wp + 4);
  float4 b0 = *(const float4*)bp, b1 = *(const float4*)(bp + 4);
  float wv[8] = {w0.x, w0.y, w0.z, w0.w, w1.x, w1.y, w1.z, w1.w};
  float bv[8] = {b0.x, b0.y, b0.z, b0.w, b1.x, b1.y, b1.z, b1.w};
  v8s o;
#pragma unroll
  for (int j = 0; j < 8; ++j) o[j] = (short)f2bf((v[j] - mean) * rstd * wv[j] + bv[j]);
  *(v8s*)(out + (size_t)row * D_HID + lane * 8) = o;
}

// ---------------------------------------------------------------------------
// gated LN: parallel = u * LN(attn0 + attn1)  (sums the two t-split partials)
// ---------------------------------------------------------------------------
__global__ __launch_bounds__(256) void gated_ln_kernel(
    const float* __restrict__ attn0, const float* __restrict__ attn1,
    const unsigned short* __restrict__ uvqk,
    const float* __restrict__ w, const float* __restrict__ b,
    unsigned short* __restrict__ par)
{
  int wid = threadIdx.x >> 6, lane = threadIdx.x & 63;
  int row = blockIdx.x * 4 + wid;
  const float* a0r = attn0 + (size_t)row * D_HID + lane * 8;
  const float* a1r = attn1 + (size_t)row * D_HID + lane * 8;
  float4 x0 = *(const float4*)a0r, x1 = *(const float4*)(a0r + 4);
  float4 y0 = *(const float4*)a1r, y1 = *(const float4*)(a1r + 4);
  float v[8] = {x0.x + y0.x, x0.y + y0.y, x0.z + y0.z, x0.w + y0.w,
                x1.x + y1.x, x1.y + y1.y, x1.z + y1.z, x1.w + y1.w};
  float s = 0.f, s2 = 0.f;
#pragma unroll
  for (int j = 0; j < 8; ++j) { s += v[j]; s2 += v[j] * v[j]; }
#pragma unroll
  for (int m = 1; m < 64; m <<= 1) { s += __shfl_xor(s, m, 64); s2 += __shfl_xor(s2, m, 64); }
  float mean = s * (1.f / D_HID);
  float var  = s2 * (1.f / D_HID) - mean * mean;
  float rstd = rsqrtf(var + EPS_);
  const float* wp = w + lane * 8; const float* bp = b + lane * 8;
  float4 w0 = *(const float4*)wp, w1 = *(const float4*)(wp + 4);
  float4 b0 = *(const float4*)bp, b1 = *(const float4*)(bp + 4);
  float wv[8] = {w0.x, w0.y, w0.z, w0.w, w1.x, w1.y, w1.z, w1.w};
  float bv[8] = {b0.x, b0.y, b0.z, b0.w, b1.x, b1.y, b1.z, b1.w};
  v8s uv = *(const v8s*)(uvqk + (size_t)row * U_DIM + lane * 8);
  v8s o;
#pragma unroll
  for (int j = 0; j < 8; ++j) {
    float u = bf2f((unsigned short)uv[j]);
    o[j] = (short)f2bf(u * ((v[j] - mean) * rstd * wv[j] + bv[j]));
  }
  *(v8s*)(par + (size_t)row * D_HID + lane * 8) = o;
}

// ---------------------------------------------------------------------------
// Transpose fp32 (R x C) -> bf16 (C x R).  32x32 LDS tiles.
// ---------------------------------------------------------------------------
__global__ __launch_bounds__(256) void transpose_w_kernel(
    const float* __restrict__ in, unsigned short* __restrict__ out, int R, int C)
{
  __shared__ float tile[32][33];
  int c0 = blockIdx.x * 32, r0 = blockIdx.y * 32;
  int tr = threadIdx.x >> 3;
  int tc = (threadIdx.x & 7) * 4;
  float4 vv = *(const float4*)(in + (size_t)(r0 + tr) * C + c0 + tc);
  tile[tr][tc + 0] = vv.x; tile[tr][tc + 1] = vv.y;
  tile[tr][tc + 2] = vv.z; tile[tr][tc + 3] = vv.w;
  __syncthreads();
  v4us o;
#pragma unroll
  for (int j = 0; j < 4; ++j) o[j] = f2bf(tile[tc + j][tr]);
  *(v4us*)(out + (size_t)(c0 + tr) * R + r0 + tc) = o;
}

// ---------------------------------------------------------------------------
// bf16 GEMM, 128x128 tile, BK=32, 4 waves (2x2 of 64x64), 16x16x32 MFMA.
// EPI 0: out_bf16 = silu(acc + bias[n])   (q columns additionally * ALPHA —
//        q is consumed only by attention, so the scale can be folded here)
// EPI 1: out_f32 = acc + resid[m][n].
// ---------------------------------------------------------------------------
template <int EPI>
__global__ __launch_bounds__(256) void gemm_kernel(
    const unsigned short* __restrict__ A, const unsigned short* __restrict__ Bt,
    int K, int N,
    const float* __restrict__ bias, const float* __restrict__ resid,
    unsigned short* __restrict__ outb, float* __restrict__ outf)
{
  __shared__ unsigned short Al[128 * 40];
  __shared__ unsigned short Bl[128 * 40];
  int m0 = blockIdx.x * 128, n0 = blockIdx.y * 128;
  int tid = threadIdx.x, lane = tid & 63, wid = tid >> 6;
  int wr = wid >> 1, wc = wid & 1;
  int lr = lane & 15, lg = lane >> 4;

  v4f acc[4][4];
#pragma unroll
  for (int i = 0; i < 4; ++i)
#pragma unroll
    for (int j = 0; j < 4; ++j) acc[i][j] = (v4f){0.f, 0.f, 0.f, 0.f};

  int srow = tid >> 1;
  int sc   = (tid & 1) * 16;
  const unsigned short* ga = A  + (size_t)(m0 + srow) * K + sc;
  const unsigned short* gb = Bt + (size_t)(n0 + srow) * K + sc;

  for (int k0 = 0; k0 < K; k0 += 32) {
    v8s a0 = *(const v8s*)(ga + k0);
    v8s a1 = *(const v8s*)(ga + k0 + 8);
    v8s b0 = *(const v8s*)(gb + k0);
    v8s b1 = *(const v8s*)(gb + k0 + 8);
    *(v8s*)&Al[srow * 40 + sc]     = a0;
    *(v8s*)&Al[srow * 40 + sc + 8] = a1;
    *(v8s*)&Bl[srow * 40 + sc]     = b0;
    *(v8s*)&Bl[srow * 40 + sc + 8] = b1;
    __syncthreads();
    v8s af[4], bf[4];
#pragma unroll
    for (int mt = 0; mt < 4; ++mt) af[mt] = *(const v8s*)&Al[(wr * 64 + mt * 16 + lr) * 40 + lg * 8];
#pragma unroll
    for (int nt = 0; nt < 4; ++nt) bf[nt] = *(const v8s*)&Bl[(wc * 64 + nt * 16 + lr) * 40 + lg * 8];
#pragma unroll
    for (int mt = 0; mt < 4; ++mt)
#pragma unroll
      for (int nt = 0; nt < 4; ++nt)
        acc[mt][nt] = __builtin_amdgcn_mfma_f32_16x16x32_bf16(af[mt], bf[nt], acc[mt][nt], 0, 0, 0);
    __syncthreads();
  }

#pragma unroll
  for (int nt = 0; nt < 4; ++nt) {
    int col = n0 + wc * 64 + nt * 16 + lr;
    float bi = 0.f;
    if constexpr (EPI == 0) bi = bias[col];
#pragma unroll
    for (int mt = 0; mt < 4; ++mt) {
      int row0 = m0 + wr * 64 + mt * 16 + lg * 4;
#pragma unroll
      for (int r = 0; r < 4; ++r) {
        float xv = acc[mt][nt][r];
        if constexpr (EPI == 0) {
          float rv = siluf(xv + bi);
          if ((unsigned)(col - 2 * D_HID) < (unsigned)D_HID) rv *= ALPHA_;  // q cols
          outb[(size_t)(row0 + r) * N + col] = f2bf(rv);
        } else {
          outf[(size_t)(row0 + r) * N + col] = xv + resid[(size_t)(row0 + r) * N + col];
        }
      }
    }
  }
}

// ---------------------------------------------------------------------------
// HSTU attention, t-split.  grid = (b 32) x (n 4) x (t-half 2) = 256 blocks.
// Block = 512 threads (8 waves); wave w owns q rows [w*32, w*32+32).
// Each block processes ALL 256 q rows of its (b,n) over 18 kv tiles of 64
// (t range [half*1152, half*1152+1152)) and writes a partial-sum buffer
// (silu attention has no normalization -> partials are additive).
//   History staged once per (b,n); tile k+1 global loads issued before the
//   compute of tile k (async reg prefetch), cvt+LDS-store after the barrier.
//   QK^T computed swapped (mfma(K,Q) -> S^T): lane holds 4 consecutive t per
//   s -> P written as packed b32 pairs; causal mask is one global compare.
// ---------------------------------------------------------------------------
__global__ __launch_bounds__(512) void attn_kernel(
    const float* __restrict__ histK, const float* __restrict__ histV,
    const unsigned short* __restrict__ uvqk, float* __restrict__ attn_out)
{
  __shared__ __align__(16) unsigned short Kl[64 * 136];     // [t][d], pad 8
  __shared__ __align__(16) unsigned short Vt[128 * 72];     // [d][t] swizzled
  __shared__ __align__(16) unsigned short Pl[8 * 32 * 72];  // per-wave [s][t]

  int bid  = blockIdx.x;
  int b    = bid >> 3;
  int n    = (bid >> 1) & 3;
  int half = bid & 1;
  int tbase0 = half * 1152;

  int tid = threadIdx.x, lane = tid & 63, w = tid >> 6;
  int lr = lane & 15, lg = lane >> 4;

  // Q fragments (A/B layouts coincide): qf[sb][c], rows s = w*32+sb*16+lr
  v8s qf[2][4];
#pragma unroll
  for (int sb = 0; sb < 2; ++sb) {
    const unsigned short* qp = uvqk + (size_t)(b * SEQ + w * 32 + sb * 16 + lr) * U_DIM
                               + 2 * D_HID + n * DHEAD + lg * 8;
#pragma unroll
    for (int c = 0; c < 4; ++c) qf[sb][c] = *(const v8s*)(qp + c * 32);
  }

  v4f oacc[2][8];
#pragma unroll
  for (int sb = 0; sb < 2; ++sb)
#pragma unroll
    for (int dt = 0; dt < 8; ++dt) oacc[sb][dt] = (v4f){0.f, 0.f, 0.f, 0.f};

  int std0  = (tid & 15) * 8;   // staging d offset (8 contiguous)
  int strow = tid >> 4;         // staging t row base (0..31)

  // staging registers (next tile in flight)
  float4 hx[2][4];              // hist path: [p][kx0,kx1,vx0,vx1]
  v8s    nx[2][2];              // new-kv path: [p][k,v]
  int isnew_r = 0;

  auto stage_load = [&](int kt) {
    int tb = tbase0 + kt * 64;
    if (tb < HIST) {
      isnew_r = 0;
#pragma unroll
      for (int p = 0; p < 2; ++p) {
        int tg = tb + p * 32 + strow;
        const float* kp = histK + ((size_t)(b * HIST + tg) * NHEAD + n) * DHEAD + std0;
        const float* vp = histV + ((size_t)(b * HIST + tg) * NHEAD + n) * DHEAD + std0;
        hx[p][0] = *(const float4*)kp;
        hx[p][1] = *(const float4*)(kp + 4);
        hx[p][2] = *(const float4*)vp;
        hx[p][3] = *(const float4*)(vp + 4);
      }
    } else {
      isnew_r = 1;
#pragma unroll
      for (int p = 0; p < 2; ++p) {
        int srw = b * SEQ + (tb - HIST) + p * 32 + strow;
        nx[p][0] = *(const v8s*)(uvqk + (size_t)srw * U_DIM + 3 * D_HID + n * DHEAD + std0);
        nx[p][1] = *(const v8s*)(uvqk + (size_t)srw * U_DIM + 1 * D_HID + n * DHEAD + std0);
      }
    }
  };

  auto stage_store = [&]() {
#pragma unroll
    for (int p = 0; p < 2; ++p) {
      int tloc = p * 32 + strow;
      v8s kv, vv;
      if (!isnew_r) {
        float kf8[8] = {hx[p][0].x, hx[p][0].y, hx[p][0].z, hx[p][0].w,
                        hx[p][1].x, hx[p][1].y, hx[p][1].z, hx[p][1].w};
        float vf8[8] = {hx[p][2].x, hx[p][2].y, hx[p][2].z, hx[p][2].w,
                        hx[p][3].x, hx[p][3].y, hx[p][3].z, hx[p][3].w};
#pragma unroll
        for (int j = 0; j < 8; ++j) { kv[j] = (short)f2bf(kf8[j]); vv[j] = (short)f2bf(vf8[j]); }
      } else {
        kv = nx[p][0]; vv = nx[p][1];
      }
      *(v8s*)&Kl[tloc * 136 + std0] = kv;
#pragma unroll
      for (int j = 0; j < 8; ++j) {
        int d = std0 + j;
        int f = (d ^ (d >> 4)) & 7;
        int slot = ((tloc >> 3) ^ f) & 7;
        Vt[d * 72 + slot * 8 + (tloc & 7)] = (unsigned short)vv[j];
      }
    }
  };

  stage_load(0);
  stage_store();
  __syncthreads();

  unsigned short* Plw = &Pl[w * 32 * 72];

  for (int kt = 0; kt < 18; ++kt) {
    if (kt + 1 < 18) stage_load(kt + 1);   // issue next-tile loads (hide under compute)

    int tb = tbase0 + kt * 64;
    bool masked = (tb >= HIST);            // tile entirely in new-token range

    // ---- QK^T swapped: D[t][s] = K . Q^T (alpha pre-folded into q) ----
#pragma unroll
    for (int tt = 0; tt < 4; ++tt) {
      v8s kf[4];
#pragma unroll
      for (int c = 0; c < 4; ++c)
        kf[c] = *(const v8s*)&Kl[(tt * 16 + lr) * 136 + c * 32 + lg * 8];
#pragma unroll
      for (int sb = 0; sb < 2; ++sb) {
        v4f sa = (v4f){0.f, 0.f, 0.f, 0.f};
#pragma unroll
        for (int c = 0; c < 4; ++c)
          sa = __builtin_amdgcn_mfma_f32_16x16x32_bf16(kf[c], qf[sb][c], sa, 0, 0, 0);
        int s  = w * 32 + sb * 16 + lr;     // query index within SEQ
        int t0 = tb + tt * 16 + lg * 4;     // global kv position of r=0
#pragma unroll
        for (int rp = 0; rp < 2; ++rp) {
          float p0 = siluf(sa[rp * 2]);
          float p1 = siluf(sa[rp * 2 + 1]);
          if (masked) {
            if (t0 + rp * 2     - HIST > s) p0 = 0.f;   // causal: t <= H + s
            if (t0 + rp * 2 + 1 - HIST > s) p1 = 0.f;
          }
          unsigned int pk = ((unsigned int)f2bf(p1) << 16) | (unsigned int)f2bf(p0);
          *(unsigned int*)&Plw[(sb * 16 + lr) * 72 + tt * 16 + lg * 4 + rp * 2] = pk;
        }
      }
    }

    // ---- PV: oacc += P . V  (Pl is per-wave: no barrier needed in between) ----
#pragma unroll
    for (int c = 0; c < 2; ++c) {
      v8s pa[2];
#pragma unroll
      for (int sb = 0; sb < 2; ++sb)
        pa[sb] = *(const v8s*)&Plw[(sb * 16 + lr) * 72 + c * 32 + lg * 8];
#pragma unroll
      for (int dt = 0; dt < 8; ++dt) {
        int d = dt * 16 + lr;
        int f = (d ^ (d >> 4)) & 7;
        int slot = ((c * 4 + lg) ^ f) & 7;
        v8s vf = *(const v8s*)&Vt[d * 72 + slot * 8];
#pragma unroll
        for (int sb = 0; sb < 2; ++sb)
          oacc[sb][dt] = __builtin_amdgcn_mfma_f32_16x16x32_bf16(pa[sb], vf, oacc[sb][dt], 0, 0, 0);
      }
    }
    __syncthreads();                        // all waves done with Kl/Vt
    if (kt + 1 < 18) {
      stage_store();                        // cvt + LDS write of next tile
      __syncthreads();
    }
  }

  // ---- epilogue: write fp32 partial rows for this t-half ----
#pragma unroll
  for (int sb = 0; sb < 2; ++sb) {
    int srow = b * SEQ + w * 32 + sb * 16 + lg * 4;
    float* op = attn_out + (size_t)half * ((size_t)NTOK * D_HID)
              + (size_t)srow * D_HID + n * DHEAD + lr;
#pragma unroll
    for (int dt = 0; dt < 8; ++dt)
#pragma unroll
      for (int r = 0; r < 4; ++r)
        op[(size_t)r * D_HID + dt * 16] = oacc[sb][dt][r];
  }
}

// ---------------------------------------------------------------------------
extern "C" void kernel_launch(void* const* d_in, const int* in_sizes, int n_in,
                              void* d_out, int out_size, void* d_ws, size_t ws_size,
                              hipStream_t stream)
{
  (void)in_sizes; (void)n_in; (void)out_size; (void)ws_size;

  const float* layer_input = (const float*)d_in[0];
  const float* hist_k   = (const float*)d_in[1];
  const float* hist_v   = (const float*)d_in[2];
  const float* ln_in_w  = (const float*)d_in[3];
  const float* ln_in_b  = (const float*)d_in[4];
  const float* W_uvqk   = (const float*)d_in[5];
  const float* b_uvqk   = (const float*)d_in[6];
  const float* ln_out_w = (const float*)d_in[7];
  const float* ln_out_b = (const float*)d_in[8];
  const float* W_proj   = (const float*)d_in[9];
  float* out = (float*)d_out;

  // workspace layout (lifetimes: x_bf ends at gemm1; attn1 starts at attn ->
  // x_bf and attn1 share [48,64) MiB):
  char* ws = (char*)d_ws;
  unsigned short* uvqk    = (unsigned short*)(ws);                  // [ 0,32) MiB
  float*          attn0   = (float*)         (ws + (32u << 20));    // [32,48)
  float*          attn1   = (float*)         (ws + (48u << 20));    // [48,64)
  unsigned short* x_bf    = (unsigned short*)(ws + (48u << 20));    // [48,56) (dead before attn)
  unsigned short* par     = (unsigned short*)(ws + (64u << 20));    // [64,72)
  unsigned short* wt_uvqk = (unsigned short*)(ws + (72u << 20));    // [72,74)
  unsigned short* wt_proj = (unsigned short*)(ws + (74u << 20));    // [74,74.5)

  ln_in_kernel<<<dim3(2048), dim3(256), 0, stream>>>(layer_input, ln_in_w, ln_in_b, x_bf);
  transpose_w_kernel<<<dim3(64, 16), dim3(256), 0, stream>>>(W_uvqk, wt_uvqk, 512, 2048);
  transpose_w_kernel<<<dim3(16, 16), dim3(256), 0, stream>>>(W_proj, wt_proj, 512, 512);
  gemm_kernel<0><<<dim3(64, 16), dim3(256), 0, stream>>>(x_bf, wt_uvqk, 512, 2048,
                                                         b_uvqk, nullptr, uvqk, nullptr);
  attn_kernel<<<dim3(256), dim3(512), 0, stream>>>(hist_k, hist_v, uvqk, attn0);
  gated_ln_kernel<<<dim3(2048), dim3(256), 0, stream>>>(attn0, attn1, uvqk, ln_out_w, ln_out_b, par);
  gemm_kernel<1><<<dim3(64, 4), dim3(256), 0, stream>>>(par, wt_proj, 512, 512,
                                                        nullptr, layer_input, nullptr, out);
}